// Round 1
// baseline (541.164 us; speedup 1.0000x reference)
//
#include <hip/hip_runtime.h>
#include <math.h>

// OnlineTripletLoss on MI355X.
// Round 0: correct fp32 baseline.
//   dominant cost: 2 passes of a 4096x4096x512 fp32 "GEMM" (dist matrix),
//   pass1 -> hp (hardest positive) & hn_fallback, pass2 -> semi-hard min + count.
// ws layout (4-byte words): [0,N) sq | [N,2N) hp | [2N,3N) hn_fall | [3N,4N) hn_semi | [4N] cnt

constexpr float MARGIN = 0.3f;
constexpr float BIG    = 1e6f;

__global__ void init_kernel(unsigned int* hp, unsigned int* hn_fall,
                            unsigned int* hn_semi, unsigned int* cnt, int N) {
    int i = blockIdx.x * 256 + threadIdx.x;
    if (i < N) {
        hp[i]      = 0u;           // 0.0f bits (max identity for non-negative floats)
        hn_fall[i] = 0u;
        hn_semi[i] = 0x7f800000u;  // +inf bits (min identity)
    }
    if (i == 0) cnt[0] = 0u;
}

// one wave per row: sq[i] = sum_k e[i][k]^2
__global__ void sq_kernel(const float* __restrict__ e, float* __restrict__ sq,
                          int N, int D) {
    int row  = blockIdx.x * 4 + (threadIdx.x >> 6);
    int lane = threadIdx.x & 63;
    if (row >= N) return;
    const float* er = e + (size_t)row * D;
    float s = 0.f;
    for (int k = lane; k < D; k += 64) { float v = er[k]; s += v * v; }
    #pragma unroll
    for (int off = 32; off; off >>= 1) s += __shfl_down(s, off, 64);
    if (lane == 0) sq[row] = s;
}

// PASS 1: hp = max(dist * pos), hn_fall = max(dist * neg)    (per row, atomics on bits)
// PASS 2: hn_semi = min(semi ? dist : dist + BIG), cnt += #semi  (needs hp complete)
template <int PASS>
__global__ __launch_bounds__(256)
void dist_pass_kernel(const float* __restrict__ e, const int* __restrict__ labels,
                      const float* __restrict__ sq,
                      unsigned int* __restrict__ hp,
                      unsigned int* __restrict__ hn_fall,
                      unsigned int* __restrict__ hn_semi,
                      unsigned int* __restrict__ semi_cnt,
                      int N, int D) {
    constexpr int TM = 64, TN = 64, BK = 32;
    // +4 pad keeps float4 LDS reads 16B-aligned (272B row) and breaks pow2 strides
    __shared__ __attribute__((aligned(16))) float As[BK][TM + 4];
    __shared__ __attribute__((aligned(16))) float Bs[BK][TN + 4];
    __shared__ float red[TM][17];
    __shared__ float sq_r[TM], sq_c[TN], hp_r[TM];
    __shared__ int   lab_r[TM], lab_c[TN];
    __shared__ unsigned int blk_cnt;

    const int tid = threadIdx.x;
    const int tx = tid & 15, ty = tid >> 4;            // 16x16 thread grid, 4x4 micro
    const int rowBase = blockIdx.y * TM;
    const int colBase = blockIdx.x * TN;

    if (tid < TM) {
        sq_r[tid]  = sq[rowBase + tid];
        lab_r[tid] = labels[rowBase + tid];
        if (PASS == 2) hp_r[tid] = __uint_as_float(hp[rowBase + tid]);
    } else if (tid < TM + TN) {
        int t = tid - TM;
        sq_c[t]  = sq[colBase + t];
        lab_c[t] = labels[colBase + t];
    }
    if (PASS == 2 && tid == 0) blk_cnt = 0u;

    float acc[4][4] = {};
    const int r0 = tid >> 3;          // 0..31  (row within half-tile)
    const int kq = (tid & 7) * 4;     // float4 k-offset within BK

    for (int kk = 0; kk < D; kk += BK) {
        __syncthreads();
        {   // stage A,B K-slices transposed: As[k][r], Bs[k][c]
            const float4 a0 = *(const float4*)&e[(size_t)(rowBase + r0)      * D + kk + kq];
            const float4 a1 = *(const float4*)&e[(size_t)(rowBase + 32 + r0) * D + kk + kq];
            const float4 b0 = *(const float4*)&e[(size_t)(colBase + r0)      * D + kk + kq];
            const float4 b1 = *(const float4*)&e[(size_t)(colBase + 32 + r0) * D + kk + kq];
            As[kq + 0][r0] = a0.x; As[kq + 1][r0] = a0.y; As[kq + 2][r0] = a0.z; As[kq + 3][r0] = a0.w;
            As[kq + 0][r0 + 32] = a1.x; As[kq + 1][r0 + 32] = a1.y; As[kq + 2][r0 + 32] = a1.z; As[kq + 3][r0 + 32] = a1.w;
            Bs[kq + 0][r0] = b0.x; Bs[kq + 1][r0] = b0.y; Bs[kq + 2][r0] = b0.z; Bs[kq + 3][r0] = b0.w;
            Bs[kq + 0][r0 + 32] = b1.x; Bs[kq + 1][r0 + 32] = b1.y; Bs[kq + 2][r0 + 32] = b1.z; Bs[kq + 3][r0 + 32] = b1.w;
        }
        __syncthreads();
        #pragma unroll
        for (int k = 0; k < BK; ++k) {
            float4 a = *(const float4*)&As[k][ty * 4];
            float4 b = *(const float4*)&Bs[k][tx * 4];
            float av[4] = {a.x, a.y, a.z, a.w};
            float bv[4] = {b.x, b.y, b.z, b.w};
            #pragma unroll
            for (int i = 0; i < 4; ++i)
                #pragma unroll
                for (int j = 0; j < 4; ++j)
                    acc[i][j] += av[i] * bv[j];
        }
    }

    // epilogue: distances + masks + per-thread partials
    float vmax_pos[4], vmax_neg[4], vmin_cand[4];
    unsigned int my_cnt = 0u;
    #pragma unroll
    for (int i = 0; i < 4; ++i) {
        vmax_pos[i] = 0.f; vmax_neg[i] = 0.f; vmin_cand[i] = 3.0e38f;
        const int r = ty * 4 + i;
        const float hpv = (PASS == 2) ? hp_r[r] : 0.f;
        #pragma unroll
        for (int j = 0; j < 4; ++j) {
            const int c = tx * 4 + j;
            float d2   = sq_r[r] + sq_c[c] - 2.0f * acc[i][j];
            float dist = sqrtf(fmaxf(d2, 1e-12f));
            bool  pos  = (lab_r[r] == lab_c[c]);
            if (PASS == 1) {
                vmax_pos[i] = fmaxf(vmax_pos[i], pos ? dist : 0.0f);
                vmax_neg[i] = fmaxf(vmax_neg[i], pos ? 0.0f : dist);
            } else {
                bool semi = (!pos) && (dist > hpv) && (dist < hpv + MARGIN);
                my_cnt += semi ? 1u : 0u;
                vmin_cand[i] = fminf(vmin_cand[i], semi ? dist : (dist + BIG));
            }
        }
    }

    if (PASS == 1) {
        __syncthreads();
        #pragma unroll
        for (int i = 0; i < 4; ++i) red[ty * 4 + i][tx] = vmax_pos[i];
        __syncthreads();
        if (tid < TM) {
            float m = red[tid][0];
            #pragma unroll
            for (int t = 1; t < 16; ++t) m = fmaxf(m, red[tid][t]);
            atomicMax(&hp[rowBase + tid], __float_as_uint(m));
        }
        __syncthreads();
        #pragma unroll
        for (int i = 0; i < 4; ++i) red[ty * 4 + i][tx] = vmax_neg[i];
        __syncthreads();
        if (tid < TM) {
            float m = red[tid][0];
            #pragma unroll
            for (int t = 1; t < 16; ++t) m = fmaxf(m, red[tid][t]);
            atomicMax(&hn_fall[rowBase + tid], __float_as_uint(m));
        }
    } else {
        __syncthreads();
        #pragma unroll
        for (int i = 0; i < 4; ++i) red[ty * 4 + i][tx] = vmin_cand[i];
        __syncthreads();
        if (tid < TM) {
            float m = red[tid][0];
            #pragma unroll
            for (int t = 1; t < 16; ++t) m = fminf(m, red[tid][t]);
            atomicMin(&hn_semi[rowBase + tid], __float_as_uint(m));
        }
        if (my_cnt) atomicAdd(&blk_cnt, my_cnt);
        __syncthreads();
        if (tid == 0 && blk_cnt) atomicAdd(semi_cnt, blk_cnt);
    }
}

__global__ void final_kernel(const unsigned int* __restrict__ hp,
                             const unsigned int* __restrict__ hn_fall,
                             const unsigned int* __restrict__ hn_semi,
                             const unsigned int* __restrict__ cnt,
                             float* __restrict__ out, int N) {
    __shared__ float ssum[256];
    __shared__ int   scnt[256];
    const bool has_semi = (cnt[0] > 0u);
    float sum = 0.f; int valid = 0;
    for (int i = threadIdx.x; i < N; i += 256) {
        float h  = __uint_as_float(hp[i]);
        float hn = has_semi ? __uint_as_float(hn_semi[i]) : __uint_as_float(hn_fall[i]);
        float t  = fmaxf(h - hn + MARGIN, 0.f);
        sum += t;
        valid += (t > 0.f) ? 1 : 0;
    }
    ssum[threadIdx.x] = sum; scnt[threadIdx.x] = valid;
    __syncthreads();
    for (int s = 128; s; s >>= 1) {
        if (threadIdx.x < (unsigned)s) {
            ssum[threadIdx.x] += ssum[threadIdx.x + s];
            scnt[threadIdx.x] += scnt[threadIdx.x + s];
        }
        __syncthreads();
    }
    if (threadIdx.x == 0) {
        float total = ssum[0]; int v = scnt[0];
        out[0] = (v > 0) ? (total / (float)v) : (total / (float)N);
    }
}

extern "C" void kernel_launch(void* const* d_in, const int* in_sizes, int n_in,
                              void* d_out, int out_size, void* d_ws, size_t ws_size,
                              hipStream_t stream) {
    const float* e      = (const float*)d_in[0];
    const int*   labels = (const int*)d_in[1];
    const int N = in_sizes[1];
    const int D = in_sizes[0] / N;
    float* out = (float*)d_out;

    float*        sq      = (float*)d_ws;
    unsigned int* hp      = (unsigned int*)d_ws + N;
    unsigned int* hn_fall = hp + N;
    unsigned int* hn_semi = hn_fall + N;
    unsigned int* cnt     = hn_semi + N;

    init_kernel<<<(N + 255) / 256, 256, 0, stream>>>(hp, hn_fall, hn_semi, cnt, N);
    sq_kernel<<<N / 4, 256, 0, stream>>>(e, sq, N, D);

    dim3 grid(N / 64, N / 64);
    dist_pass_kernel<1><<<grid, 256, 0, stream>>>(e, labels, sq, hp, hn_fall, hn_semi, cnt, N, D);
    dist_pass_kernel<2><<<grid, 256, 0, stream>>>(e, labels, sq, hp, hn_fall, hn_semi, cnt, N, D);

    final_kernel<<<1, 256, 0, stream>>>(hp, hn_fall, hn_semi, cnt, out, N);
}

// Round 2
// 340.531 us; speedup vs baseline: 1.5892x; 1.5892x over previous
//
#include <hip/hip_runtime.h>
#include <math.h>

// OnlineTripletLoss on MI355X — Round 2.
// R1 baseline: 541 us, two 264-us fp32 GEMM passes, VALUBusy 62%, 2.5e7 LDS conflicts.
// Changes: (a) 128x128 tile / 8x8 micro-tile (split 4+4, stride-64) -> FMA:LDS ratio 4x,
//          (b) materialize dist matrix to ws in pass 1; pass 2 = memory-bound row scan.
// ws layout: [0,N) sq | [N,2N) hp | [2N,3N) hn_fall | [3N,4N) hn_semi | [4N] cnt | pad | dist[N*N]

constexpr float MARGIN = 0.3f;
constexpr float BIG    = 1e6f;

__global__ void init_kernel(unsigned int* hp, unsigned int* hn_fall,
                            unsigned int* hn_semi, unsigned int* cnt, int N) {
    int i = blockIdx.x * 256 + threadIdx.x;
    if (i < N) {
        hp[i]      = 0u;           // 0.0f bits (max identity for non-negative floats)
        hn_fall[i] = 0u;
        hn_semi[i] = 0x7f800000u;  // +inf bits (min identity)
    }
    if (i == 0) cnt[0] = 0u;
}

// one wave per row: sq[i] = sum_k e[i][k]^2
__global__ void sq_kernel(const float* __restrict__ e, float* __restrict__ sq,
                          int N, int D) {
    int row  = blockIdx.x * 4 + (threadIdx.x >> 6);
    int lane = threadIdx.x & 63;
    if (row >= N) return;
    const float* er = e + (size_t)row * D;
    float s = 0.f;
    for (int k = lane; k < D; k += 64) { float v = er[k]; s += v * v; }
    #pragma unroll
    for (int off = 32; off; off >>= 1) s += __shfl_down(s, off, 64);
    if (lane == 0) sq[row] = s;
}

// 128x128 tile, 256 threads, 8x8 micro-tile split as 4+4 with +64 offset.
// PASS 1: hp = max(dist*pos), hn_fall = max(dist*neg); optionally store dist tile.
// PASS 2 (recompute fallback): semi-hard min + count (needs hp complete).
template <int PASS, bool STORE>
__global__ __launch_bounds__(256, 4)
void dist_pass_kernel(const float* __restrict__ e, const int* __restrict__ labels,
                      const float* __restrict__ sq, float* __restrict__ gdist,
                      unsigned int* __restrict__ hp,
                      unsigned int* __restrict__ hn_fall,
                      unsigned int* __restrict__ hn_semi,
                      unsigned int* __restrict__ semi_cnt,
                      int N, int D) {
    constexpr int TM = 128, TN = 128, BK = 16;
    __shared__ __attribute__((aligned(16))) float As[BK][TM + 4];
    __shared__ __attribute__((aligned(16))) float Bs[BK][TN + 4];
    __shared__ float red[TM][17];
    __shared__ float sq_r[TM], sq_c[TN], hp_r[TM];
    __shared__ int   lab_r[TM], lab_c[TN];
    __shared__ unsigned int blk_cnt;

    const int tid = threadIdx.x;
    const int tx = tid & 15, ty = tid >> 4;            // 16x16 thread grid
    const int rowBase = blockIdx.y * TM;
    const int colBase = blockIdx.x * TN;

    if (tid < TM) {
        sq_r[tid]  = sq[rowBase + tid];
        lab_r[tid] = labels[rowBase + tid];
        if (PASS == 2) hp_r[tid] = __uint_as_float(hp[rowBase + tid]);
    } else {
        int t = tid - TM;
        sq_c[t]  = sq[colBase + t];
        lab_c[t] = labels[colBase + t];
    }
    if (PASS == 2 && tid == 0) blk_cnt = 0u;

    float acc[8][8] = {};
    const int r0 = tid >> 1;          // 0..127 : staging row within tile
    const int kc = (tid & 1) * 8;     // 0 or 8 : staging k-offset

    for (int kk = 0; kk < D; kk += BK) {
        __syncthreads();
        {   // stage A,B K-slices transposed: As[k][r], Bs[k][c]
            const float* ga = &e[(size_t)(rowBase + r0) * D + kk + kc];
            const float* gb = &e[(size_t)(colBase + r0) * D + kk + kc];
            const float4 alo = *(const float4*)ga;
            const float4 ahi = *(const float4*)(ga + 4);
            const float4 blo = *(const float4*)gb;
            const float4 bhi = *(const float4*)(gb + 4);
            As[kc + 0][r0] = alo.x; As[kc + 1][r0] = alo.y; As[kc + 2][r0] = alo.z; As[kc + 3][r0] = alo.w;
            As[kc + 4][r0] = ahi.x; As[kc + 5][r0] = ahi.y; As[kc + 6][r0] = ahi.z; As[kc + 7][r0] = ahi.w;
            Bs[kc + 0][r0] = blo.x; Bs[kc + 1][r0] = blo.y; Bs[kc + 2][r0] = blo.z; Bs[kc + 3][r0] = blo.w;
            Bs[kc + 4][r0] = bhi.x; Bs[kc + 5][r0] = bhi.y; Bs[kc + 6][r0] = bhi.z; Bs[kc + 7][r0] = bhi.w;
        }
        __syncthreads();
        #pragma unroll
        for (int k = 0; k < BK; ++k) {
            const float4 a0 = *(const float4*)&As[k][ty * 4];
            const float4 a1 = *(const float4*)&As[k][64 + ty * 4];
            const float4 b0 = *(const float4*)&Bs[k][tx * 4];
            const float4 b1 = *(const float4*)&Bs[k][64 + tx * 4];
            const float av[8] = {a0.x, a0.y, a0.z, a0.w, a1.x, a1.y, a1.z, a1.w};
            const float bv[8] = {b0.x, b0.y, b0.z, b0.w, b1.x, b1.y, b1.z, b1.w};
            #pragma unroll
            for (int i = 0; i < 8; ++i)
                #pragma unroll
                for (int j = 0; j < 8; ++j)
                    acc[i][j] += av[i] * bv[j];
        }
    }

    // epilogue: convert acc -> dist in place
    #pragma unroll
    for (int i = 0; i < 8; ++i) {
        const int r = (i < 4) ? (ty * 4 + i) : (64 + ty * 4 + i - 4);
        #pragma unroll
        for (int j = 0; j < 8; ++j) {
            const int c = (j < 4) ? (tx * 4 + j) : (64 + tx * 4 + j - 4);
            float d2 = sq_r[r] + sq_c[c] - 2.0f * acc[i][j];
            acc[i][j] = sqrtf(fmaxf(d2, 1e-12f));
        }
    }

    if (STORE) {
        #pragma unroll
        for (int i = 0; i < 8; ++i) {
            const int r = (i < 4) ? (ty * 4 + i) : (64 + ty * 4 + i - 4);
            float* gr = &gdist[(size_t)(rowBase + r) * N + colBase];
            *(float4*)&gr[tx * 4]      = make_float4(acc[i][0], acc[i][1], acc[i][2], acc[i][3]);
            *(float4*)&gr[64 + tx * 4] = make_float4(acc[i][4], acc[i][5], acc[i][6], acc[i][7]);
        }
    }

    if (PASS == 1) {
        float vmax_pos[8], vmax_neg[8];
        #pragma unroll
        for (int i = 0; i < 8; ++i) {
            vmax_pos[i] = 0.f; vmax_neg[i] = 0.f;
            const int r = (i < 4) ? (ty * 4 + i) : (64 + ty * 4 + i - 4);
            #pragma unroll
            for (int j = 0; j < 8; ++j) {
                const int c = (j < 4) ? (tx * 4 + j) : (64 + tx * 4 + j - 4);
                bool pos = (lab_r[r] == lab_c[c]);
                vmax_pos[i] = fmaxf(vmax_pos[i], pos ? acc[i][j] : 0.0f);
                vmax_neg[i] = fmaxf(vmax_neg[i], pos ? 0.0f : acc[i][j]);
            }
        }
        #pragma unroll
        for (int i = 0; i < 8; ++i) {
            const int r = (i < 4) ? (ty * 4 + i) : (64 + ty * 4 + i - 4);
            red[r][tx] = vmax_pos[i];
        }
        __syncthreads();
        if (tid < TM) {
            float m = red[tid][0];
            #pragma unroll
            for (int t = 1; t < 16; ++t) m = fmaxf(m, red[tid][t]);
            atomicMax(&hp[rowBase + tid], __float_as_uint(m));
        }
        __syncthreads();
        #pragma unroll
        for (int i = 0; i < 8; ++i) {
            const int r = (i < 4) ? (ty * 4 + i) : (64 + ty * 4 + i - 4);
            red[r][tx] = vmax_neg[i];
        }
        __syncthreads();
        if (tid < TM) {
            float m = red[tid][0];
            #pragma unroll
            for (int t = 1; t < 16; ++t) m = fmaxf(m, red[tid][t]);
            atomicMax(&hn_fall[rowBase + tid], __float_as_uint(m));
        }
    } else {
        float vmin[8];
        unsigned int my_cnt = 0u;
        #pragma unroll
        for (int i = 0; i < 8; ++i) {
            vmin[i] = 3.0e38f;
            const int r = (i < 4) ? (ty * 4 + i) : (64 + ty * 4 + i - 4);
            const float hpv = hp_r[r];
            #pragma unroll
            for (int j = 0; j < 8; ++j) {
                const int c = (j < 4) ? (tx * 4 + j) : (64 + tx * 4 + j - 4);
                float dist = acc[i][j];
                bool pos = (lab_r[r] == lab_c[c]);
                bool semi = (!pos) && (dist > hpv) && (dist < hpv + MARGIN);
                my_cnt += semi ? 1u : 0u;
                vmin[i] = fminf(vmin[i], semi ? dist : (dist + BIG));
            }
        }
        #pragma unroll
        for (int i = 0; i < 8; ++i) {
            const int r = (i < 4) ? (ty * 4 + i) : (64 + ty * 4 + i - 4);
            red[r][tx] = vmin[i];
        }
        __syncthreads();
        if (tid < TM) {
            float m = red[tid][0];
            #pragma unroll
            for (int t = 1; t < 16; ++t) m = fminf(m, red[tid][t]);
            atomicMin(&hn_semi[rowBase + tid], __float_as_uint(m));
        }
        if (my_cnt) atomicAdd(&blk_cnt, my_cnt);
        __syncthreads();
        if (tid == 0 && blk_cnt) atomicAdd(semi_cnt, blk_cnt);
    }
}

// Stored-dist pass 2: one block per row, memory-bound scan of dist[row][*].
__global__ __launch_bounds__(256)
void semi_row_kernel(const float* __restrict__ gdist, const int* __restrict__ labels,
                     const unsigned int* __restrict__ hp,
                     unsigned int* __restrict__ hn_semi,
                     unsigned int* __restrict__ semi_cnt, int N) {
    __shared__ float smin[4];
    __shared__ unsigned int scnt[4];
    const int row  = blockIdx.x;
    const float hpv = __uint_as_float(hp[row]);
    const int  labr = labels[row];
    const float* dr = gdist + (size_t)row * N;

    float vmin = 3.0e38f;
    unsigned int c = 0u;
    for (int c0 = threadIdx.x * 4; c0 < N; c0 += 1024) {
        const float4 d = *(const float4*)&dr[c0];
        const int4   l = *(const int4*)&labels[c0];
        const float dv[4] = {d.x, d.y, d.z, d.w};
        const int   lv[4] = {l.x, l.y, l.z, l.w};
        #pragma unroll
        for (int j = 0; j < 4; ++j) {
            bool semi = (lv[j] != labr) && (dv[j] > hpv) && (dv[j] < hpv + MARGIN);
            c += semi ? 1u : 0u;
            vmin = fminf(vmin, semi ? dv[j] : (dv[j] + BIG));
        }
    }
    #pragma unroll
    for (int off = 32; off; off >>= 1) {
        vmin = fminf(vmin, __shfl_down(vmin, off, 64));
        c   += __shfl_down(c, off, 64);
    }
    const int lane = threadIdx.x & 63, wid = threadIdx.x >> 6;
    if (lane == 0) { smin[wid] = vmin; scnt[wid] = c; }
    __syncthreads();
    if (threadIdx.x == 0) {
        float m = fminf(fminf(smin[0], smin[1]), fminf(smin[2], smin[3]));
        unsigned int tc = scnt[0] + scnt[1] + scnt[2] + scnt[3];
        hn_semi[row] = __float_as_uint(m);
        if (tc) atomicAdd(semi_cnt, tc);
    }
}

__global__ void final_kernel(const unsigned int* __restrict__ hp,
                             const unsigned int* __restrict__ hn_fall,
                             const unsigned int* __restrict__ hn_semi,
                             const unsigned int* __restrict__ cnt,
                             float* __restrict__ out, int N) {
    __shared__ float ssum[256];
    __shared__ int   scnt[256];
    const bool has_semi = (cnt[0] > 0u);
    float sum = 0.f; int valid = 0;
    for (int i = threadIdx.x; i < N; i += 256) {
        float h  = __uint_as_float(hp[i]);
        float hn = has_semi ? __uint_as_float(hn_semi[i]) : __uint_as_float(hn_fall[i]);
        float t  = fmaxf(h - hn + MARGIN, 0.f);
        sum += t;
        valid += (t > 0.f) ? 1 : 0;
    }
    ssum[threadIdx.x] = sum; scnt[threadIdx.x] = valid;
    __syncthreads();
    for (int s = 128; s; s >>= 1) {
        if (threadIdx.x < (unsigned)s) {
            ssum[threadIdx.x] += ssum[threadIdx.x + s];
            scnt[threadIdx.x] += scnt[threadIdx.x + s];
        }
        __syncthreads();
    }
    if (threadIdx.x == 0) {
        float total = ssum[0]; int v = scnt[0];
        out[0] = (v > 0) ? (total / (float)v) : (total / (float)N);
    }
}

extern "C" void kernel_launch(void* const* d_in, const int* in_sizes, int n_in,
                              void* d_out, int out_size, void* d_ws, size_t ws_size,
                              hipStream_t stream) {
    const float* e      = (const float*)d_in[0];
    const int*   labels = (const int*)d_in[1];
    const int N = in_sizes[1];
    const int D = in_sizes[0] / N;
    float* out = (float*)d_out;

    float*        sq      = (float*)d_ws;
    unsigned int* hp      = (unsigned int*)d_ws + N;
    unsigned int* hn_fall = hp + N;
    unsigned int* hn_semi = hn_fall + N;
    unsigned int* cnt     = hn_semi + N;

    size_t small_bytes = ((size_t)(4 * N + 1) * 4 + 255) & ~(size_t)255;
    float* gdist = (float*)((char*)d_ws + small_bytes);
    const bool use_stored = ws_size >= small_bytes + (size_t)N * N * sizeof(float);

    init_kernel<<<(N + 255) / 256, 256, 0, stream>>>(hp, hn_fall, hn_semi, cnt, N);
    sq_kernel<<<N / 4, 256, 0, stream>>>(e, sq, N, D);

    dim3 grid(N / 128, N / 128);
    if (use_stored) {
        dist_pass_kernel<1, true><<<grid, 256, 0, stream>>>(e, labels, sq, gdist, hp, hn_fall, hn_semi, cnt, N, D);
        semi_row_kernel<<<N, 256, 0, stream>>>(gdist, labels, hp, hn_semi, cnt, N);
    } else {
        dist_pass_kernel<1, false><<<grid, 256, 0, stream>>>(e, labels, sq, gdist, hp, hn_fall, hn_semi, cnt, N, D);
        dist_pass_kernel<2, false><<<grid, 256, 0, stream>>>(e, labels, sq, gdist, hp, hn_fall, hn_semi, cnt, N, D);
    }
    final_kernel<<<1, 256, 0, stream>>>(hp, hn_fall, hn_semi, cnt, out, N);
}

// Round 3
// 222.156 us; speedup vs baseline: 2.4360x; 1.5328x over previous
//
#include <hip/hip_runtime.h>
#include <math.h>

// OnlineTripletLoss on MI355X — Round 3.
// R2: 340 us; dist pass pinned at 74 TF = 94% of the SCALAR fp32 FMA ceiling (78.6 TF).
// Change: move the pairwise-distance GEMM to the matrix pipe via split-f16:
//   e = hi + lo (f16); E.E^T = hi.hi + hi.lo + lo.hi  (one MFMA GEMM, K_eff = 3D = 1536,
//   section-remapped staging; rel err ~2^-22, dist err ~1e-5).
// ws: sq[N] | hp[N] | hn_fall[N] | hn_semi[N] | cnt | pad | ehl[N][2D] f16 | dist[N*N] f32

constexpr float MARGIN = 0.3f;
constexpr float BIG    = 1e6f;

typedef _Float16 half8   __attribute__((ext_vector_type(8)));
typedef float    floatx16 __attribute__((ext_vector_type(16)));

__global__ void init_kernel(unsigned int* hp, unsigned int* hn_fall,
                            unsigned int* hn_semi, unsigned int* cnt, int N) {
    int i = blockIdx.x * 256 + threadIdx.x;
    if (i < N) {
        hp[i]      = 0u;           // max identity (dist >= 0)
        hn_fall[i] = 0u;
        hn_semi[i] = 0x7f800000u;  // +inf (min identity)
    }
    if (i == 0) cnt[0] = 0u;
}

// sq[i] = sum_k e[i][k]^2, fp32 (one wave per row)
__global__ void sq_kernel(const float* __restrict__ e, float* __restrict__ sq,
                          int N, int D) {
    int row  = blockIdx.x * 4 + (threadIdx.x >> 6);
    int lane = threadIdx.x & 63;
    if (row >= N) return;
    const float* er = e + (size_t)row * D;
    float s = 0.f;
    for (int k = lane; k < D; k += 64) { float v = er[k]; s += v * v; }
    #pragma unroll
    for (int off = 32; off; off >>= 1) s += __shfl_down(s, off, 64);
    if (lane == 0) sq[row] = s;
}

// split e into f16 hi/lo: ehl[row][0..D) = hi, ehl[row][D..2D) = lo
__global__ void convert_kernel(const float* __restrict__ e, _Float16* __restrict__ ehl,
                               int N, int D) {
    int base = (blockIdx.x * 256 + threadIdx.x) * 8;
    if (base >= N * D) return;
    int row = base / D, k = base - row * D;
    const float4 x0 = *(const float4*)&e[base];
    const float4 x1 = *(const float4*)&e[base + 4];
    const float xv[8] = {x0.x, x0.y, x0.z, x0.w, x1.x, x1.y, x1.z, x1.w};
    half8 hi, lo;
    #pragma unroll
    for (int j = 0; j < 8; ++j) {
        _Float16 h = (_Float16)xv[j];
        hi[j] = h;
        lo[j] = (_Float16)(xv[j] - (float)h);
    }
    _Float16* dst = &ehl[(size_t)row * 2 * D + k];
    *(half8*)dst       = hi;
    *(half8*)(dst + D) = lo;
}

// MFMA distance pass. 128x128 tile, 4 waves, each 64x64 via 2x2 mfma_f32_32x32x16_f16.
// K_eff = 3D with section remap: A = [hi, hi, lo], B = [hi, lo, hi].
// PASS 1: hp / hn_fall row maxima (+ optional dist store). PASS 2: semi-hard min + count.
template <int PASS, bool STORE>
__global__ __launch_bounds__(256, 2)
void mfma_pass_kernel(const _Float16* __restrict__ ehl, const int* __restrict__ labels,
                      const float* __restrict__ sq, float* __restrict__ gdist,
                      unsigned int* __restrict__ hp,
                      unsigned int* __restrict__ hn_fall,
                      unsigned int* __restrict__ hn_semi,
                      unsigned int* __restrict__ semi_cnt,
                      int N, int D) {
    constexpr int TM = 128, TN = 128, BK = 32, LST = 48; // 48-halve stride: 16B-aligned, <=2-way banks
    __shared__ __attribute__((aligned(16))) _Float16 As[TM][LST];
    __shared__ __attribute__((aligned(16))) _Float16 Bs[TN][LST];
    __shared__ float sq_r[TM], sq_c[TN], hp_r[TM];
    __shared__ int   lab_r[TM], lab_c[TN];
    __shared__ unsigned int blk_cnt;

    const int tid  = threadIdx.x;
    const int lane = tid & 63;
    const int wave = tid >> 6;
    const int wr = (wave >> 1) * 64;   // wave's row offset in tile
    const int wc = (wave & 1) * 64;    // wave's col offset in tile
    const int mrow = lane & 31;
    const int koff = (lane >> 5) * 8;
    const int half_id = lane >> 5;
    const int ln = lane & 31;
    const int rowBase = blockIdx.y * TM;
    const int colBase = blockIdx.x * TN;

    if (tid < TM) {
        sq_r[tid]  = sq[rowBase + tid];
        lab_r[tid] = labels[rowBase + tid];
        if (PASS == 2) hp_r[tid] = __uint_as_float(hp[rowBase + tid]);
    } else {
        int t = tid - TM;
        sq_c[t]  = sq[colBase + t];
        lab_c[t] = labels[colBase + t];
    }
    if (PASS == 2 && tid == 0) blk_cnt = 0u;

    floatx16 acc[2][2];
    #pragma unroll
    for (int i = 0; i < 2; ++i)
        #pragma unroll
        for (int j = 0; j < 2; ++j)
            #pragma unroll
            for (int r = 0; r < 16; ++r) acc[i][j][r] = 0.f;

    const size_t rs = (size_t)2 * D;   // ehl row stride (halves)

    #pragma unroll 1
    for (int s = 0; s < 3; ++s) {
        const int abase = (s == 2) ? D : 0;   // A sections: hi, hi, lo
        const int bbase = (s == 1) ? D : 0;   // B sections: hi, lo, hi
        #pragma unroll 1
        for (int kk = 0; kk < D; kk += BK) {
            __syncthreads();
            #pragma unroll
            for (int i = 0; i < 2; ++i) {
                const int idx = tid + i * 256;
                const int r = idx >> 2, sg = (idx & 3) * 8;
                *(half8*)&As[r][sg] = *(const half8*)&ehl[(size_t)(rowBase + r) * rs + abase + kk + sg];
                *(half8*)&Bs[r][sg] = *(const half8*)&ehl[(size_t)(colBase + r) * rs + bbase + kk + sg];
            }
            __syncthreads();
            #pragma unroll
            for (int ks = 0; ks < 2; ++ks) {
                const half8 a0 = *(const half8*)&As[wr + mrow][ks * 16 + koff];
                const half8 a1 = *(const half8*)&As[wr + 32 + mrow][ks * 16 + koff];
                const half8 b0 = *(const half8*)&Bs[wc + mrow][ks * 16 + koff];
                const half8 b1 = *(const half8*)&Bs[wc + 32 + mrow][ks * 16 + koff];
                acc[0][0] = __builtin_amdgcn_mfma_f32_32x32x16_f16(a0, b0, acc[0][0], 0, 0, 0);
                acc[0][1] = __builtin_amdgcn_mfma_f32_32x32x16_f16(a0, b1, acc[0][1], 0, 0, 0);
                acc[1][0] = __builtin_amdgcn_mfma_f32_32x32x16_f16(a1, b0, acc[1][0], 0, 0, 0);
                acc[1][1] = __builtin_amdgcn_mfma_f32_32x32x16_f16(a1, b1, acc[1][1], 0, 0, 0);
            }
        }
    }

    // epilogue: C/D layout col = lane&31, row = (reg&3) + 8*(reg>>2) + 4*(lane>>5)
    const float sqc0 = sq_c[wc + ln];
    const float sqc1 = sq_c[wc + 32 + ln];
    const int   lc0  = lab_c[wc + ln];
    const int   lc1  = lab_c[wc + 32 + ln];

    #pragma unroll
    for (int bi = 0; bi < 2; ++bi) {
        #pragma unroll
        for (int r = 0; r < 16; ++r) {
            const int lrow = wr + bi * 32 + (r & 3) + 8 * (r >> 2) + 4 * half_id;
            const int grow = rowBase + lrow;
            const float sqr = sq_r[lrow];
            const int   lr  = lab_r[lrow];
            float d0 = sqrtf(fmaxf(sqr + sqc0 - 2.0f * acc[bi][0][r], 1e-12f));
            float d1 = sqrtf(fmaxf(sqr + sqc1 - 2.0f * acc[bi][1][r], 1e-12f));
            if (STORE) {
                gdist[(size_t)grow * N + colBase + wc + ln]      = d0;
                gdist[(size_t)grow * N + colBase + wc + 32 + ln] = d1;
            }
            const bool p0 = (lr == lc0), p1 = (lr == lc1);
            if (PASS == 1) {
                float vp = fmaxf(p0 ? d0 : 0.f, p1 ? d1 : 0.f);
                float vn = fmaxf(p0 ? 0.f : d0, p1 ? 0.f : d1);
                #pragma unroll
                for (int off = 16; off; off >>= 1) {
                    vp = fmaxf(vp, __shfl_xor(vp, off, 64));
                    vn = fmaxf(vn, __shfl_xor(vn, off, 64));
                }
                if (ln == 0) {
                    atomicMax(&hp[grow],      __float_as_uint(vp));
                    atomicMax(&hn_fall[grow], __float_as_uint(vn));
                }
            } else {
                const float hpv = hp_r[lrow];
                const bool s0 = !p0 && (d0 > hpv) && (d0 < hpv + MARGIN);
                const bool s1 = !p1 && (d1 > hpv) && (d1 < hpv + MARGIN);
                unsigned int c = (unsigned)s0 + (unsigned)s1;
                float vm = fminf(s0 ? d0 : d0 + BIG, s1 ? d1 : d1 + BIG);
                #pragma unroll
                for (int off = 16; off; off >>= 1) {
                    vm = fminf(vm, __shfl_xor(vm, off, 64));
                    c += __shfl_xor(c, off, 64);
                }
                if (ln == 0) {
                    atomicMin(&hn_semi[grow], __float_as_uint(vm));
                    if (c) atomicAdd(&blk_cnt, c);
                }
            }
        }
    }
    if (PASS == 2) {
        __syncthreads();
        if (tid == 0 && blk_cnt) atomicAdd(semi_cnt, blk_cnt);
    }
}

// Stored-dist pass 2: one block per row, memory-bound scan of dist[row][*].
__global__ __launch_bounds__(256)
void semi_row_kernel(const float* __restrict__ gdist, const int* __restrict__ labels,
                     const unsigned int* __restrict__ hp,
                     unsigned int* __restrict__ hn_semi,
                     unsigned int* __restrict__ semi_cnt, int N) {
    __shared__ float smin[4];
    __shared__ unsigned int scnt[4];
    const int row  = blockIdx.x;
    const float hpv = __uint_as_float(hp[row]);
    const int  labr = labels[row];
    const float* dr = gdist + (size_t)row * N;

    float vmin = 3.0e38f;
    unsigned int c = 0u;
    for (int c0 = threadIdx.x * 4; c0 < N; c0 += 1024) {
        const float4 d = *(const float4*)&dr[c0];
        const int4   l = *(const int4*)&labels[c0];
        const float dv[4] = {d.x, d.y, d.z, d.w};
        const int   lv[4] = {l.x, l.y, l.z, l.w};
        #pragma unroll
        for (int j = 0; j < 4; ++j) {
            bool semi = (lv[j] != labr) && (dv[j] > hpv) && (dv[j] < hpv + MARGIN);
            c += semi ? 1u : 0u;
            vmin = fminf(vmin, semi ? dv[j] : (dv[j] + BIG));
        }
    }
    #pragma unroll
    for (int off = 32; off; off >>= 1) {
        vmin = fminf(vmin, __shfl_down(vmin, off, 64));
        c   += __shfl_down(c, off, 64);
    }
    const int lane = threadIdx.x & 63, wid = threadIdx.x >> 6;
    if (lane == 0) { smin[wid] = vmin; scnt[wid] = c; }
    __syncthreads();
    if (threadIdx.x == 0) {
        float m = fminf(fminf(smin[0], smin[1]), fminf(smin[2], smin[3]));
        unsigned int tc = scnt[0] + scnt[1] + scnt[2] + scnt[3];
        hn_semi[row] = __float_as_uint(m);
        if (tc) atomicAdd(semi_cnt, tc);
    }
}

__global__ void final_kernel(const unsigned int* __restrict__ hp,
                             const unsigned int* __restrict__ hn_fall,
                             const unsigned int* __restrict__ hn_semi,
                             const unsigned int* __restrict__ cnt,
                             float* __restrict__ out, int N) {
    __shared__ float ssum[256];
    __shared__ int   scnt[256];
    const bool has_semi = (cnt[0] > 0u);
    float sum = 0.f; int valid = 0;
    for (int i = threadIdx.x; i < N; i += 256) {
        float h  = __uint_as_float(hp[i]);
        float hn = has_semi ? __uint_as_float(hn_semi[i]) : __uint_as_float(hn_fall[i]);
        float t  = fmaxf(h - hn + MARGIN, 0.f);
        sum += t;
        valid += (t > 0.f) ? 1 : 0;
    }
    ssum[threadIdx.x] = sum; scnt[threadIdx.x] = valid;
    __syncthreads();
    for (int s = 128; s; s >>= 1) {
        if (threadIdx.x < (unsigned)s) {
            ssum[threadIdx.x] += ssum[threadIdx.x + s];
            scnt[threadIdx.x] += scnt[threadIdx.x + s];
        }
        __syncthreads();
    }
    if (threadIdx.x == 0) {
        float total = ssum[0]; int v = scnt[0];
        out[0] = (v > 0) ? (total / (float)v) : (total / (float)N);
    }
}

extern "C" void kernel_launch(void* const* d_in, const int* in_sizes, int n_in,
                              void* d_out, int out_size, void* d_ws, size_t ws_size,
                              hipStream_t stream) {
    const float* e      = (const float*)d_in[0];
    const int*   labels = (const int*)d_in[1];
    const int N = in_sizes[1];
    const int D = in_sizes[0] / N;
    float* out = (float*)d_out;

    float*        sq      = (float*)d_ws;
    unsigned int* hp      = (unsigned int*)d_ws + N;
    unsigned int* hn_fall = hp + N;
    unsigned int* hn_semi = hn_fall + N;
    unsigned int* cnt     = hn_semi + N;

    const size_t small_bytes = ((size_t)(4 * N + 1) * 4 + 255) & ~(size_t)255;
    const size_t ehl_bytes   = (size_t)N * D * 2 * sizeof(_Float16); // hi+lo
    _Float16* ehl   = (_Float16*)((char*)d_ws + small_bytes);
    float*    gdist = (float*)((char*)d_ws + small_bytes + ehl_bytes);
    const bool use_stored = ws_size >= small_bytes + ehl_bytes + (size_t)N * N * sizeof(float);

    init_kernel<<<(N + 255) / 256, 256, 0, stream>>>(hp, hn_fall, hn_semi, cnt, N);
    sq_kernel<<<N / 4, 256, 0, stream>>>(e, sq, N, D);
    convert_kernel<<<(N * D / 8 + 255) / 256, 256, 0, stream>>>(e, ehl, N, D);

    dim3 grid(N / 128, N / 128);
    if (use_stored) {
        mfma_pass_kernel<1, true><<<grid, 256, 0, stream>>>(ehl, labels, sq, gdist, hp, hn_fall, hn_semi, cnt, N, D);
        semi_row_kernel<<<N, 256, 0, stream>>>(gdist, labels, hp, hn_semi, cnt, N);
    } else {
        mfma_pass_kernel<1, false><<<grid, 256, 0, stream>>>(ehl, labels, sq, gdist, hp, hn_fall, hn_semi, cnt, N, D);
        mfma_pass_kernel<2, false><<<grid, 256, 0, stream>>>(ehl, labels, sq, gdist, hp, hn_fall, hn_semi, cnt, N, D);
    }
    final_kernel<<<1, 256, 0, stream>>>(hp, hn_fall, hn_semi, cnt, out, N);
}

// Round 4
// 194.597 us; speedup vs baseline: 2.7810x; 1.1416x over previous
//
#include <hip/hip_runtime.h>
#include <math.h>

// OnlineTripletLoss on MI355X — Round 4.
// R3: 222 us = 101 us MFMA pass + ~110 us dist-matrix round trip (73MB write + 64MB scan),
//     plus 1.26e7 LDS bank conflicts (LST=48 stride: bank-start 24r mod 32, 4-phase pileup).
// Changes:
//  (1) hn_semi = min{d : neg, d > hp} (no upper bound) is loss-equivalent -> phase 2 needs
//      only the acc registers. Single fused kernel with a device-scope spin barrier
//      (512 blocks, 2/CU co-residency by construction: LDS 65KB, launch_bounds(256,2)).
//  (2) LST=40 (80B row stride = 20 banks): minimal-conflict ds_read_b128 across rows.
//  (3) 128x256 block tile, wave = 64x128 (2x4 frags): 12 frag reads / 24 MFMAs,
//      hi+lo staged per-kk so every ehl byte is read once per tile.
// ws: sq[N] | hp[N] | hn_fall[N] | hn_semi[N] | bar | pad | ehl[N][2D] f16

constexpr float MARGIN = 0.3f;

typedef _Float16 half8    __attribute__((ext_vector_type(8)));
typedef float    floatx16 __attribute__((ext_vector_type(16)));

__global__ void init_kernel(unsigned int* hp, unsigned int* hn_fall,
                            unsigned int* hn_semi, unsigned int* bar, int N) {
    int i = blockIdx.x * 256 + threadIdx.x;
    if (i < N) {
        hp[i]      = 0u;           // max identity (dist >= 0)
        hn_fall[i] = 0u;
        hn_semi[i] = 0x7f800000u;  // +inf (min identity)
    }
    if (i == 0) bar[0] = 0u;
}

// sq[i] = sum_k e[i][k]^2, fp32 (one wave per row)
__global__ void sq_kernel(const float* __restrict__ e, float* __restrict__ sq,
                          int N, int D) {
    int row  = blockIdx.x * 4 + (threadIdx.x >> 6);
    int lane = threadIdx.x & 63;
    if (row >= N) return;
    const float* er = e + (size_t)row * D;
    float s = 0.f;
    for (int k = lane; k < D; k += 64) { float v = er[k]; s += v * v; }
    #pragma unroll
    for (int off = 32; off; off >>= 1) s += __shfl_down(s, off, 64);
    if (lane == 0) sq[row] = s;
}

// split e into f16 hi/lo: ehl[row][0..D) = hi, ehl[row][D..2D) = lo
__global__ void convert_kernel(const float* __restrict__ e, _Float16* __restrict__ ehl,
                               int N, int D) {
    int base = (blockIdx.x * 256 + threadIdx.x) * 8;
    if (base >= N * D) return;
    int row = base / D, k = base - row * D;
    const float4 x0 = *(const float4*)&e[base];
    const float4 x1 = *(const float4*)&e[base + 4];
    const float xv[8] = {x0.x, x0.y, x0.z, x0.w, x1.x, x1.y, x1.z, x1.w};
    half8 hi, lo;
    #pragma unroll
    for (int j = 0; j < 8; ++j) {
        _Float16 h = (_Float16)xv[j];
        hi[j] = h;
        lo[j] = (_Float16)(xv[j] - (float)h);
    }
    _Float16* dst = &ehl[(size_t)row * 2 * D + k];
    *(half8*)dst       = hi;
    *(half8*)(dst + D) = lo;
}

// Fused two-phase kernel. Block tile 128x256, 4 waves each 64x128 (2x4 of 32x32x16 f16).
// dot = sum_k (hi.hi + hi.lo + lo.hi); acc held in registers across a grid spin-barrier.
__global__ __launch_bounds__(256, 2)
void fused_kernel(const _Float16* __restrict__ ehl, const int* __restrict__ labels,
                  const float* __restrict__ sq,
                  unsigned int* __restrict__ hp,
                  unsigned int* __restrict__ hn_fall,
                  unsigned int* __restrict__ hn_semi,
                  unsigned int* __restrict__ bar,
                  int N, int D, unsigned int nblocks) {
    constexpr int TM = 128, TN = 256, BK = 32, LST = 40; // 80B stride = 20 banks: uniform b128
    __shared__ __attribute__((aligned(16))) _Float16 Ah[TM][LST];
    __shared__ __attribute__((aligned(16))) _Float16 Al[TM][LST];
    __shared__ __attribute__((aligned(16))) _Float16 Bh[TN][LST];
    __shared__ __attribute__((aligned(16))) _Float16 Bl[TN][LST];
    __shared__ float sq_r[TM], sq_c[TN], hp_r[TM];
    __shared__ int   lab_r[TM], lab_c[TN];

    const int tid  = threadIdx.x;
    const int lane = tid & 63;
    const int wave = tid >> 6;
    const int wr = (wave >> 1) * 64;    // wave row offset
    const int wc = (wave & 1) * 128;    // wave col offset
    const int mrow = lane & 31;
    const int half_id = lane >> 5;
    const int koff = half_id * 8;
    const int rowBase = blockIdx.y * TM;
    const int colBase = blockIdx.x * TN;

    sq_c[tid]  = sq[colBase + tid];
    lab_c[tid] = labels[colBase + tid];
    if (tid < TM) {
        sq_r[tid]  = sq[rowBase + tid];
        lab_r[tid] = labels[rowBase + tid];
    }

    floatx16 acc[2][4];
    #pragma unroll
    for (int i = 0; i < 2; ++i)
        #pragma unroll
        for (int j = 0; j < 4; ++j)
            #pragma unroll
            for (int r = 0; r < 16; ++r) acc[i][j][r] = 0.f;

    const size_t rs = (size_t)2 * D;

    #pragma unroll 1
    for (int kk = 0; kk < D; kk += BK) {
        __syncthreads();
        #pragma unroll
        for (int i = 0; i < 2; ++i) {
            const int idx = tid + i * 256;            // 512 chunks for A
            const int r = idx >> 2, c8 = (idx & 3) * 8;
            const size_t ga = (size_t)(rowBase + r) * rs + kk + c8;
            *(half8*)&Ah[r][c8] = *(const half8*)&ehl[ga];
            *(half8*)&Al[r][c8] = *(const half8*)&ehl[ga + D];
        }
        #pragma unroll
        for (int i = 0; i < 4; ++i) {
            const int idx = tid + i * 256;            // 1024 chunks for B
            const int r = idx >> 2, c8 = (idx & 3) * 8;
            const size_t gb = (size_t)(colBase + r) * rs + kk + c8;
            *(half8*)&Bh[r][c8] = *(const half8*)&ehl[gb];
            *(half8*)&Bl[r][c8] = *(const half8*)&ehl[gb + D];
        }
        __syncthreads();
        #pragma unroll
        for (int ks = 0; ks < 2; ++ks) {
            const int off = ks * 16 + koff;
            const half8 ah0 = *(const half8*)&Ah[wr + mrow][off];
            const half8 ah1 = *(const half8*)&Ah[wr + 32 + mrow][off];
            const half8 al0 = *(const half8*)&Al[wr + mrow][off];
            const half8 al1 = *(const half8*)&Al[wr + 32 + mrow][off];
            #pragma unroll
            for (int j = 0; j < 4; ++j) {
                const half8 bh = *(const half8*)&Bh[wc + j * 32 + mrow][off];
                const half8 bl = *(const half8*)&Bl[wc + j * 32 + mrow][off];
                acc[0][j] = __builtin_amdgcn_mfma_f32_32x32x16_f16(ah0, bh, acc[0][j], 0, 0, 0);
                acc[1][j] = __builtin_amdgcn_mfma_f32_32x32x16_f16(ah1, bh, acc[1][j], 0, 0, 0);
                acc[0][j] = __builtin_amdgcn_mfma_f32_32x32x16_f16(ah0, bl, acc[0][j], 0, 0, 0);
                acc[1][j] = __builtin_amdgcn_mfma_f32_32x32x16_f16(ah1, bl, acc[1][j], 0, 0, 0);
                acc[0][j] = __builtin_amdgcn_mfma_f32_32x32x16_f16(al0, bh, acc[0][j], 0, 0, 0);
                acc[1][j] = __builtin_amdgcn_mfma_f32_32x32x16_f16(al1, bh, acc[1][j], 0, 0, 0);
            }
        }
    }

    // per-lane column metadata (C/D layout: col = mrow within each 32-col frag)
    float sqcv[4]; int lcv[4];
    #pragma unroll
    for (int j = 0; j < 4; ++j) {
        sqcv[j] = sq_c[wc + j * 32 + mrow];
        lcv[j]  = lab_c[wc + j * 32 + mrow];
    }

    // ---- phase 1: hp (hardest positive), hn_fall (hardest negative) row maxima ----
    #pragma unroll
    for (int bi = 0; bi < 2; ++bi) {
        #pragma unroll
        for (int r = 0; r < 16; ++r) {
            const int lrow = wr + bi * 32 + (r & 3) + 8 * (r >> 2) + 4 * half_id;
            const float sqr = sq_r[lrow];
            const int   lr  = lab_r[lrow];
            float vp = 0.f, vn = 0.f;
            #pragma unroll
            for (int j = 0; j < 4; ++j) {
                float d = sqrtf(fmaxf(sqr + sqcv[j] - 2.0f * acc[bi][j][r], 1e-12f));
                bool pos = (lr == lcv[j]);
                vp = fmaxf(vp, pos ? d : 0.f);
                vn = fmaxf(vn, pos ? 0.f : d);
            }
            #pragma unroll
            for (int off = 16; off; off >>= 1) {   // reduce over 32 cols (stays in half)
                vp = fmaxf(vp, __shfl_xor(vp, off, 64));
                vn = fmaxf(vn, __shfl_xor(vn, off, 64));
            }
            if (mrow == 0) {
                atomicMax(&hp[rowBase + lrow],      __float_as_uint(vp));
                atomicMax(&hn_fall[rowBase + lrow], __float_as_uint(vn));
            }
        }
    }

    // ---- grid spin barrier (all 512 blocks co-resident: LDS 65KB -> 2 blocks/CU) ----
    __syncthreads();                 // drains this block's atomics (vmcnt(0) before barrier)
    if (tid == 0) {
        __threadfence();
        atomicAdd(bar, 1u);
        while (atomicAdd(bar, 0u) < nblocks) __builtin_amdgcn_s_sleep(8);
        __threadfence();
    }
    __syncthreads();
    if (tid < TM)                    // device-scope read of completed hp
        hp_r[tid] = __uint_as_float(atomicMax(&hp[rowBase + tid], 0u));
    __syncthreads();

    // ---- phase 2: hn_semi = min{d : neg, d > hp} from retained acc ----
    #pragma unroll
    for (int bi = 0; bi < 2; ++bi) {
        #pragma unroll
        for (int r = 0; r < 16; ++r) {
            const int lrow = wr + bi * 32 + (r & 3) + 8 * (r >> 2) + 4 * half_id;
            const float sqr = sq_r[lrow];
            const int   lr  = lab_r[lrow];
            const float hpv = hp_r[lrow];
            float vm = __builtin_inff();
            #pragma unroll
            for (int j = 0; j < 4; ++j) {
                float d = sqrtf(fmaxf(sqr + sqcv[j] - 2.0f * acc[bi][j][r], 1e-12f));
                bool cand = (lr != lcv[j]) && (d > hpv);
                vm = fminf(vm, cand ? d : __builtin_inff());
            }
            #pragma unroll
            for (int off = 16; off; off >>= 1)
                vm = fminf(vm, __shfl_xor(vm, off, 64));
            if (mrow == 0)
                atomicMin(&hn_semi[rowBase + lrow], __float_as_uint(vm));
        }
    }
}

__global__ void final_kernel(const unsigned int* __restrict__ hp,
                             const unsigned int* __restrict__ hn_fall,
                             const unsigned int* __restrict__ hn_semi,
                             float* __restrict__ out, int N) {
    __shared__ float ssum[256];
    __shared__ int   scnt[256];
    __shared__ int   sany[256];
    int any = 0;
    for (int i = threadIdx.x; i < N; i += 256) {
        float h  = __uint_as_float(hp[i]);
        float hs = __uint_as_float(hn_semi[i]);
        any |= (hs < h + MARGIN) ? 1 : 0;   // exists semi-hard pair in this row
    }
    sany[threadIdx.x] = any;
    __syncthreads();
    for (int s = 128; s; s >>= 1) {
        if (threadIdx.x < (unsigned)s) sany[threadIdx.x] |= sany[threadIdx.x + s];
        __syncthreads();
    }
    const bool has_semi = sany[0] != 0;
    float sum = 0.f; int valid = 0;
    for (int i = threadIdx.x; i < N; i += 256) {
        float h  = __uint_as_float(hp[i]);
        float hn = has_semi ? __uint_as_float(hn_semi[i]) : __uint_as_float(hn_fall[i]);
        float t  = fmaxf(h - hn + MARGIN, 0.f);
        if (!(t > 0.f)) t = 0.f;            // -inf guard (hn=+inf rows)
        sum += t;
        valid += (t > 0.f) ? 1 : 0;
    }
    ssum[threadIdx.x] = sum; scnt[threadIdx.x] = valid;
    __syncthreads();
    for (int s = 128; s; s >>= 1) {
        if (threadIdx.x < (unsigned)s) {
            ssum[threadIdx.x] += ssum[threadIdx.x + s];
            scnt[threadIdx.x] += scnt[threadIdx.x + s];
        }
        __syncthreads();
    }
    if (threadIdx.x == 0) {
        float total = ssum[0]; int v = scnt[0];
        out[0] = (v > 0) ? (total / (float)v) : (total / (float)N);
    }
}

extern "C" void kernel_launch(void* const* d_in, const int* in_sizes, int n_in,
                              void* d_out, int out_size, void* d_ws, size_t ws_size,
                              hipStream_t stream) {
    const float* e      = (const float*)d_in[0];
    const int*   labels = (const int*)d_in[1];
    const int N = in_sizes[1];
    const int D = in_sizes[0] / N;
    float* out = (float*)d_out;

    float*        sq      = (float*)d_ws;
    unsigned int* hp      = (unsigned int*)d_ws + N;
    unsigned int* hn_fall = hp + N;
    unsigned int* hn_semi = hn_fall + N;
    unsigned int* bar     = hn_semi + N;

    const size_t small_bytes = ((size_t)(4 * N + 1) * 4 + 255) & ~(size_t)255;
    _Float16* ehl = (_Float16*)((char*)d_ws + small_bytes);

    init_kernel<<<(N + 255) / 256, 256, 0, stream>>>(hp, hn_fall, hn_semi, bar, N);
    sq_kernel<<<N / 4, 256, 0, stream>>>(e, sq, N, D);
    convert_kernel<<<(N * D / 8 + 255) / 256, 256, 0, stream>>>(e, ehl, N, D);

    dim3 grid(N / 256, N / 128);   // 16 x 32 = 512 blocks = 2 per CU, co-resident
    fused_kernel<<<grid, 256, 0, stream>>>(ehl, labels, sq, hp, hn_fall, hn_semi, bar,
                                           N, D, grid.x * grid.y);
    final_kernel<<<1, 256, 0, stream>>>(hp, hn_fall, hn_semi, out, N);
}